// Round 1
// baseline (277.935 us; speedup 1.0000x reference)
//
#include <hip/hip_runtime.h>
#include <math.h>

#define B 4
#define C 56
#define H 320
#define W 320
#define HC 313
#define WC 313
#define NIMG (H*W)          // 102400
#define NSP  (HC*WC)        // 97969
#define NPIX (B*NSP)        // 391876
#define NM   (B*NIMG)       // 409600
#define BN_EPS 1e-5f

// E[b,h,w] = exp(mean_c x[b,c,h,w])
__global__ __launch_bounds__(256) void meanexp_kernel(const float* __restrict__ x,
                                                      float* __restrict__ E) {
  int idx = blockIdx.x*256 + threadIdx.x;
  if (idx >= NM) return;
  int b = idx / NIMG, pix = idx - b*NIMG;
  const float* xp = x + (size_t)b*C*NIMG + pix;
  float s0 = 0.f, s1 = 0.f, s2 = 0.f, s3 = 0.f;
  #pragma unroll
  for (int c = 0; c < C; c += 4) {
    s0 += xp[(size_t)(c+0)*NIMG];
    s1 += xp[(size_t)(c+1)*NIMG];
    s2 += xp[(size_t)(c+2)*NIMG];
    s3 += xp[(size_t)(c+3)*NIMG];
  }
  E[idx] = expf((s0+s1+s2+s3) * (1.0f/C));
}

// 8x8 sliding box-sum (VALID), separable in LDS. in: [z][H][W] -> out: [z][HC][WC], *scale
__global__ __launch_bounds__(256) void pool_kernel(const float* __restrict__ in,
                                                   float* __restrict__ out, float scale) {
  __shared__ float tin[39][40];
  __shared__ float hs[39][33];
  const int z = blockIdx.z;
  const float* ip = in + (size_t)z*NIMG;
  float* op = out + (size_t)z*NSP;
  const int i0 = blockIdx.y*32, j0 = blockIdx.x*32;
  const int tid = threadIdx.x;
  for (int idx = tid; idx < 39*39; idx += 256) {
    int r = idx / 39, cc = idx - r*39;
    int gi = i0 + r, gj = j0 + cc;
    tin[r][cc] = (gi < H && gj < W) ? ip[gi*W + gj] : 0.f;
  }
  __syncthreads();
  for (int idx = tid; idx < 39*32; idx += 256) {
    int r = idx >> 5, j = idx & 31;
    float s = 0.f;
    #pragma unroll
    for (int d = 0; d < 8; ++d) s += tin[r][j+d];
    hs[r][j] = s;
  }
  __syncthreads();
  for (int idx = tid; idx < 32*32; idx += 256) {
    int i = idx >> 5, j = idx & 31;
    int gi = i0 + i, gj = j0 + j;
    if (gi < HC && gj < WC) {
      float s = 0.f;
      #pragma unroll
      for (int d = 0; d < 8; ++d) s += hs[i+d][j];
      op[gi*WC + gj] = s * scale;
    }
  }
}

// Pass 1 over p: per-pixel y1_o = w1[o,:]·p + b1[o]; accumulate BN1 per-channel sum/sumsq.
__global__ __launch_bounds__(256) void conv_stats_kernel(
    const float* __restrict__ p, const float* __restrict__ w1, const float* __restrict__ b1,
    float* __restrict__ stats) {
  __shared__ float w_s[C*C];
  __shared__ float b_s[C];
  __shared__ float acc1[C], acc2[C];
  const int tid = threadIdx.x;
  for (int i = tid; i < C*C; i += 256) w_s[i] = w1[i];
  if (tid < C) { b_s[tid] = b1[tid]; acc1[tid] = 0.f; acc2[tid] = 0.f; }
  __syncthreads();
  int pixIdx = blockIdx.x*256 + tid;
  bool valid = pixIdx < NPIX;
  int pi = valid ? pixIdx : 0;
  int b = pi / NSP, sp = pi - b*NSP;
  const float* pp = p + (size_t)b*C*NSP + sp;
  float pv[C];
  #pragma unroll
  for (int c = 0; c < C; ++c) pv[c] = valid ? pp[(size_t)c*NSP] : 0.f;
  for (int o = 0; o < C; ++o) {
    float y = b_s[o];
    #pragma unroll
    for (int c = 0; c < C; ++c) y = fmaf(w_s[o*C + c], pv[c], y);
    if (!valid) y = 0.f;
    float yy = y*y;
    #pragma unroll
    for (int off = 32; off > 0; off >>= 1) {
      y  += __shfl_down(y, off);
      yy += __shfl_down(yy, off);
    }
    if ((tid & 63) == 0) { atomicAdd(&acc1[o], y); atomicAdd(&acc2[o], yy); }
  }
  __syncthreads();
  if (tid < C) { atomicAdd(&stats[tid], acc1[tid]); atomicAdd(&stats[C+tid], acc2[tid]); }
}

__global__ void bn1_final_kernel(const float* __restrict__ stats,
                                 const float* __restrict__ g, const float* __restrict__ be,
                                 float* __restrict__ ac) {
  int o = threadIdx.x;
  if (o >= C) return;
  float mean = stats[o] * (1.0f/NPIX);
  float var  = stats[C+o] * (1.0f/NPIX) - mean*mean;
  float a = g[o] * rsqrtf(var + BN_EPS);
  ac[o]   = a;
  ac[C+o] = fmaf(-mean, a, be[o]);
}

// Pass 2: recompute y1, BN1+ReLU, dot with w2 -> y2; accumulate scalar BN2 stats.
__global__ __launch_bounds__(256) void y2_stats_kernel(
    const float* __restrict__ p, const float* __restrict__ w1, const float* __restrict__ b1,
    const float* __restrict__ ac, const float* __restrict__ w2, const float* __restrict__ b2,
    float* __restrict__ y2, float* __restrict__ stats2) {
  __shared__ float w_s[C*C];
  __shared__ float a_s[C], c_s[C], w2_s[C], b1_s[C];
  __shared__ float racc[2];
  const int tid = threadIdx.x;
  for (int i = tid; i < C*C; i += 256) w_s[i] = w1[i];
  if (tid < C) { a_s[tid] = ac[tid]; c_s[tid] = ac[C+tid]; w2_s[tid] = w2[tid]; b1_s[tid] = b1[tid]; }
  if (tid < 2) racc[tid] = 0.f;
  __syncthreads();
  int pixIdx = blockIdx.x*256 + tid;
  bool valid = pixIdx < NPIX;
  int pi = valid ? pixIdx : 0;
  int b = pi / NSP, sp = pi - b*NSP;
  const float* pp = p + (size_t)b*C*NSP + sp;
  float pv[C];
  #pragma unroll
  for (int c = 0; c < C; ++c) pv[c] = valid ? pp[(size_t)c*NSP] : 0.f;
  float acc = b2[0];
  for (int o = 0; o < C; ++o) {
    float y = b1_s[o];
    #pragma unroll
    for (int c = 0; c < C; ++c) y = fmaf(w_s[o*C + c], pv[c], y);
    float t = fmaxf(fmaf(a_s[o], y, c_s[o]), 0.f);
    acc = fmaf(w2_s[o], t, acc);
  }
  if (valid) y2[pixIdx] = acc;
  else acc = 0.f;
  float aa = acc*acc;
  #pragma unroll
  for (int off = 32; off > 0; off >>= 1) {
    acc += __shfl_down(acc, off);
    aa  += __shfl_down(aa, off);
  }
  if ((tid & 63) == 0) { atomicAdd(&racc[0], acc); atomicAdd(&racc[1], aa); }
  __syncthreads();
  if (tid < 2) atomicAdd(&stats2[tid], racc[tid]);
}

__global__ void bn2_final_kernel(const float* __restrict__ stats2,
                                 const float* __restrict__ g2, const float* __restrict__ be2,
                                 float* __restrict__ a2c2) {
  if (threadIdx.x == 0) {
    float mean = stats2[0] * (1.0f/NPIX);
    float var  = stats2[1] * (1.0f/NPIX) - mean*mean;
    float a = g2[0] * rsqrtf(var + BN_EPS);
    a2c2[0] = a;
    a2c2[1] = fmaf(-mean, a, be2[0]);
  }
}

// C_out = relu(a2*y2 + c2) -> d_out; T = C_out / S
__global__ __launch_bounds__(256) void cout_t_kernel(
    const float* __restrict__ y2, const float* __restrict__ a2c2,
    const float* __restrict__ S, float* __restrict__ cout, float* __restrict__ T) {
  int idx = blockIdx.x*256 + threadIdx.x;
  if (idx >= NPIX) return;
  float v = fmaxf(fmaf(a2c2[0], y2[idx], a2c2[1]), 0.f);
  cout[idx] = v;
  T[idx] = v / S[idx];
}

// R[b,h,w] = E[b,h,w] * sum over valid windows containing (h,w) of T[i,j]
__global__ __launch_bounds__(256) void r_kernel(const float* __restrict__ E,
                                                const float* __restrict__ T,
                                                float* __restrict__ R) {
  int idx = blockIdx.x*256 + threadIdx.x;
  if (idx >= NM) return;
  int b = idx / NIMG, rem = idx - b*NIMG;
  int h = rem / W, w = rem - h*W;
  int ilo = max(h-7, 0), ihi = min(h, HC-1);
  int jlo = max(w-7, 0), jhi = min(w, WC-1);
  const float* Tb = T + (size_t)b*NSP;
  float s = 0.f;
  for (int i = ilo; i <= ihi; ++i) {
    const float* Tr = Tb + i*WC;
    for (int j = jlo; j <= jhi; ++j) s += Tr[j];
  }
  R[idx] = E[idx] * s;
}

extern "C" void kernel_launch(void* const* d_in, const int* in_sizes, int n_in,
                              void* d_out, int out_size, void* d_ws, size_t ws_size,
                              hipStream_t stream) {
  const float* x   = (const float*)d_in[0];
  const float* w1  = (const float*)d_in[1];
  const float* b1  = (const float*)d_in[2];
  const float* w2  = (const float*)d_in[3];
  const float* b2  = (const float*)d_in[4];
  const float* g1  = (const float*)d_in[5];
  const float* be1 = (const float*)d_in[6];
  const float* g2  = (const float*)d_in[7];
  const float* be2 = (const float*)d_in[8];

  float* out_c = (float*)d_out;          // C_out: NPIX floats
  float* out_r = out_c + NPIX;           // R: NM floats

  float* ws = (float*)d_ws;
  size_t off = 0;
  float* p     = ws + off; off += (size_t)B*C*NSP;  // 21,945,056
  float* E     = ws + off; off += NM;               // 409,600
  float* Sarr  = ws + off; off += NPIX;             // 391,876
  float* y2    = ws + off; off += NPIX;
  float* T     = ws + off; off += NPIX;
  float* stats = ws + off; off += 114;              // [0..111] BN1 sums, [112..113] BN2
  float* ac    = ws + off; off += 112;              // BN1 scale/shift
  float* a2c2  = ws + off; off += 2;                // BN2 scale/shift

  hipMemsetAsync(stats, 0, 114*sizeof(float), stream);

  meanexp_kernel<<<(NM+255)/256, 256, 0, stream>>>(x, E);

  dim3 pg(10, 10, B*C);
  pool_kernel<<<pg, 256, 0, stream>>>(x, p, 1.0f/64.0f);

  dim3 sg(10, 10, B);
  pool_kernel<<<sg, 256, 0, stream>>>(E, Sarr, 1.0f);

  conv_stats_kernel<<<(NPIX+255)/256, 256, 0, stream>>>(p, w1, b1, stats);
  bn1_final_kernel<<<1, 64, 0, stream>>>(stats, g1, be1, ac);
  y2_stats_kernel<<<(NPIX+255)/256, 256, 0, stream>>>(p, w1, b1, ac, w2, b2, y2, stats+112);
  bn2_final_kernel<<<1, 64, 0, stream>>>(stats+112, g2, be2, a2c2);
  cout_t_kernel<<<(NPIX+255)/256, 256, 0, stream>>>(y2, a2c2, Sarr, out_c, T);
  r_kernel<<<(NM+255)/256, 256, 0, stream>>>(E, T, out_r);
}

// Round 2
// 250.692 us; speedup vs baseline: 1.1087x; 1.1087x over previous
//
#include <hip/hip_runtime.h>
#include <math.h>

#define B 4
#define C 56
#define H 320
#define W 320
#define HC 313
#define WC 313
#define NIMG (H*W)          // 102400
#define NSP  (HC*WC)        // 97969
#define NPIX (B*NSP)        // 391876
#define NM   (B*NIMG)       // 409600
#define BN_EPS 1e-5f
#define NCHUNK ((NPIX + 255)/256)   // 1531

typedef __attribute__((ext_vector_type(8))) short short8;
typedef __attribute__((ext_vector_type(16))) float float16;

// E[b,h,w] = exp(mean_c x[b,c,h,w])
__global__ __launch_bounds__(256) void meanexp_kernel(const float* __restrict__ x,
                                                      float* __restrict__ E) {
  int idx = blockIdx.x*256 + threadIdx.x;
  if (idx >= NM) return;
  int b = idx / NIMG, pix = idx - b*NIMG;
  const float* xp = x + (size_t)b*C*NIMG + pix;
  float s0 = 0.f, s1 = 0.f, s2 = 0.f, s3 = 0.f;
  #pragma unroll
  for (int c = 0; c < C; c += 4) {
    s0 += xp[(size_t)(c+0)*NIMG];
    s1 += xp[(size_t)(c+1)*NIMG];
    s2 += xp[(size_t)(c+2)*NIMG];
    s3 += xp[(size_t)(c+3)*NIMG];
  }
  E[idx] = expf((s0+s1+s2+s3) * (1.0f/C));
}

// 8x8 sliding box-sum (VALID), separable in LDS. in: [z][H][W] -> out: [z][HC][WC], *scale
__global__ __launch_bounds__(256) void pool_kernel(const float* __restrict__ in,
                                                   float* __restrict__ out, float scale) {
  __shared__ float tin[39][40];
  __shared__ float hs[39][33];
  const int z = blockIdx.z;
  const float* ip = in + (size_t)z*NIMG;
  float* op = out + (size_t)z*NSP;
  const int i0 = blockIdx.y*32, j0 = blockIdx.x*32;
  const int tid = threadIdx.x;
  for (int idx = tid; idx < 39*39; idx += 256) {
    int r = idx / 39, cc = idx - r*39;
    int gi = i0 + r, gj = j0 + cc;
    tin[r][cc] = (gi < H && gj < W) ? ip[gi*W + gj] : 0.f;
  }
  __syncthreads();
  for (int idx = tid; idx < 39*32; idx += 256) {
    int r = idx >> 5, j = idx & 31;
    float s = 0.f;
    #pragma unroll
    for (int d = 0; d < 8; ++d) s += tin[r][j+d];
    hs[r][j] = s;
  }
  __syncthreads();
  for (int idx = tid; idx < 32*32; idx += 256) {
    int i = idx >> 5, j = idx & 31;
    int gi = i0 + i, gj = j0 + j;
    if (gi < HC && gj < WC) {
      float s = 0.f;
      #pragma unroll
      for (int d = 0; d < 8; ++d) s += hs[i+d][j];
      op[gi*WC + gj] = s * scale;
    }
  }
}

// Gram of p: G[64x64] += P P^T (bf16 MFMA), gs[c] = sum_pix p[c]
__global__ __launch_bounds__(256) void gram_kernel(const float* __restrict__ p,
                                                   float* __restrict__ G,
                                                   float* __restrict__ gs) {
  __shared__ unsigned short Pl[64*256];   // bf16, XOR-swizzled rows of 512B
  __shared__ float sred[4][C];
  const int tid = threadIdx.x;
  const int wave = tid >> 6, lane = tid & 63;
  const int qi = (wave >> 1) * 32, qj = (wave & 1) * 32;
  float16 acc = {};
  float sacc[C];
  #pragma unroll
  for (int i = 0; i < C; ++i) sacc[i] = 0.f;

  for (int chunk = blockIdx.x; chunk < NCHUNK; chunk += gridDim.x) {
    int pixIdx = chunk*256 + tid;
    bool valid = pixIdx < NPIX;
    int pi = valid ? pixIdx : 0;
    int b = pi / NSP, sp = pi - b*NSP;
    const float* pp = p + (size_t)b*C*NSP + sp;
    __syncthreads();   // previous iteration's reads of Pl are done
    #pragma unroll
    for (int i = 0; i < 64; ++i) {
      float v = 0.f;
      if (i < C) {
        v = valid ? pp[(size_t)i*NSP] : 0.f;
        sacc[i] += v;
      }
      // f32 -> bf16 round-to-nearest-even
      unsigned int u = __float_as_uint(v);
      unsigned short r = (unsigned short)((u + 0x7fffu + ((u >> 16) & 1u)) >> 16);
      int byte = i*512 + ((2*tid) ^ ((i & 15) << 4));
      *(unsigned short*)((char*)Pl + byte) = r;
    }
    __syncthreads();
    #pragma unroll
    for (int ks = 0; ks < 16; ++ks) {
      int ka = ks*16 + 8*(lane >> 5);
      int rA = qi + (lane & 31);
      int rB = qj + (lane & 31);
      short8 a  = *(const short8*)((const char*)Pl + rA*512 + ((2*ka) ^ ((rA & 15) << 4)));
      short8 bb = *(const short8*)((const char*)Pl + rB*512 + ((2*ka) ^ ((rB & 15) << 4)));
      acc = __builtin_amdgcn_mfma_f32_32x32x16_bf16(a, bb, acc, 0, 0, 0);
    }
  }
  // flush Gram quadrant (each (gr,gc) hit once per block)
  #pragma unroll
  for (int reg = 0; reg < 16; ++reg) {
    int gr = qi + (reg & 3) + 8*(reg >> 2) + 4*(lane >> 5);
    int gc = qj + (lane & 31);
    atomicAdd(&G[gr*64 + gc], acc[reg]);
  }
  // reduce per-channel sums
  #pragma unroll
  for (int i = 0; i < C; ++i) {
    float v = sacc[i];
    #pragma unroll
    for (int off = 32; off > 0; off >>= 1) v += __shfl_down(v, off);
    if (lane == 0) sred[wave][i] = v;
  }
  __syncthreads();
  if (tid < C) {
    float v = sred[0][tid] + sred[1][tid] + sred[2][tid] + sred[3][tid];
    atomicAdd(&gs[tid], v);
  }
}

// BN1 scale/shift analytically from Gram: mean = w.m + b1, Var = wGw'/N - (w.m)^2
__global__ __launch_bounds__(256) void bn1_from_gram_kernel(
    const float* __restrict__ G, const float* __restrict__ gs,
    const float* __restrict__ w1, const float* __restrict__ b1,
    const float* __restrict__ g1, const float* __restrict__ be1,
    float* __restrict__ ac) {
  __shared__ float Gl[64*64];
  __shared__ float Wl[C*C];
  __shared__ float Ul[C*C];
  __shared__ float ml[C];
  int tid = threadIdx.x;
  for (int i = tid; i < 64*64; i += 256) Gl[i] = G[i];
  for (int i = tid; i < C*C; i += 256) Wl[i] = w1[i];
  if (tid < C) ml[tid] = gs[tid] * (1.0f/NPIX);
  __syncthreads();
  for (int e = tid; e < C*C; e += 256) {
    int o = e / C, c = e - o*C;
    float s = 0.f;
    for (int c2 = 0; c2 < C; ++c2) s = fmaf(Wl[o*C + c2], Gl[c2*64 + c], s);
    Ul[e] = s;
  }
  __syncthreads();
  if (tid < C) {
    int o = tid;
    float q = 0.f, uw = 0.f;
    for (int c = 0; c < C; ++c) {
      q  = fmaf(Wl[o*C + c], ml[c], q);
      uw = fmaf(Ul[o*C + c], Wl[o*C + c], uw);
    }
    float var = uw * (1.0f/NPIX) - q*q;
    float mean = q + b1[o];
    float a = g1[o] * rsqrtf(var + BN_EPS);
    ac[o]     = a;
    ac[C + o] = fmaf(-mean, a, be1[o]);
  }
}

// y2 pass: y1 = w1.p (+b1), BN1+ReLU, dot w2 -> y2; BN2 stats. Weights via uniform
// (scalar) loads -- no LDS staging, inner loop is pure v_fmac with SGPR operand.
__global__ __launch_bounds__(256) void y2_stats_kernel(
    const float* __restrict__ p, const float* __restrict__ w1, const float* __restrict__ b1,
    const float* __restrict__ ac, const float* __restrict__ w2, const float* __restrict__ b2,
    float* __restrict__ y2, float* __restrict__ stats2) {
  __shared__ float racc[2];
  const int tid = threadIdx.x;
  if (tid < 2) racc[tid] = 0.f;
  __syncthreads();
  int pixIdx = blockIdx.x*256 + tid;
  bool valid = pixIdx < NPIX;
  int pi = valid ? pixIdx : 0;
  int b = pi / NSP, sp = pi - b*NSP;
  const float* pp = p + (size_t)b*C*NSP + sp;
  float pv[C];
  #pragma unroll
  for (int c = 0; c < C; ++c) pv[c] = valid ? pp[(size_t)c*NSP] : 0.f;
  float acc = b2[0];
  for (int o = 0; o < C; ++o) {
    float y = b1[o];
    #pragma unroll
    for (int c = 0; c < C; ++c) y = fmaf(w1[o*C + c], pv[c], y);
    float t = fmaxf(fmaf(ac[o], y, ac[C + o]), 0.f);
    acc = fmaf(w2[o], t, acc);
  }
  if (valid) y2[pixIdx] = acc;
  else acc = 0.f;
  float aa = acc*acc;
  #pragma unroll
  for (int off = 32; off > 0; off >>= 1) {
    acc += __shfl_down(acc, off);
    aa  += __shfl_down(aa, off);
  }
  if ((tid & 63) == 0) { atomicAdd(&racc[0], acc); atomicAdd(&racc[1], aa); }
  __syncthreads();
  if (tid < 2) atomicAdd(&stats2[tid], racc[tid]);
}

__global__ void bn2_final_kernel(const float* __restrict__ stats2,
                                 const float* __restrict__ g2, const float* __restrict__ be2,
                                 float* __restrict__ a2c2) {
  if (threadIdx.x == 0) {
    float mean = stats2[0] * (1.0f/NPIX);
    float var  = stats2[1] * (1.0f/NPIX) - mean*mean;
    float a = g2[0] * rsqrtf(var + BN_EPS);
    a2c2[0] = a;
    a2c2[1] = fmaf(-mean, a, be2[0]);
  }
}

// C_out = relu(a2*y2 + c2) -> d_out; T = C_out / S
__global__ __launch_bounds__(256) void cout_t_kernel(
    const float* __restrict__ y2, const float* __restrict__ a2c2,
    const float* __restrict__ S, float* __restrict__ cout, float* __restrict__ T) {
  int idx = blockIdx.x*256 + threadIdx.x;
  if (idx >= NPIX) return;
  float v = fmaxf(fmaf(a2c2[0], y2[idx], a2c2[1]), 0.f);
  cout[idx] = v;
  T[idx] = v / S[idx];
}

// R[b,h,w] = E[b,h,w] * sum over valid windows containing (h,w) of T[i,j]
__global__ __launch_bounds__(256) void r_kernel(const float* __restrict__ E,
                                                const float* __restrict__ T,
                                                float* __restrict__ R) {
  int idx = blockIdx.x*256 + threadIdx.x;
  if (idx >= NM) return;
  int b = idx / NIMG, rem = idx - b*NIMG;
  int h = rem / W, w = rem - h*W;
  int ilo = max(h-7, 0), ihi = min(h, HC-1);
  int jlo = max(w-7, 0), jhi = min(w, WC-1);
  const float* Tb = T + (size_t)b*NSP;
  float s = 0.f;
  for (int i = ilo; i <= ihi; ++i) {
    const float* Tr = Tb + i*WC;
    for (int j = jlo; j <= jhi; ++j) s += Tr[j];
  }
  R[idx] = E[idx] * s;
}

extern "C" void kernel_launch(void* const* d_in, const int* in_sizes, int n_in,
                              void* d_out, int out_size, void* d_ws, size_t ws_size,
                              hipStream_t stream) {
  const float* x   = (const float*)d_in[0];
  const float* w1  = (const float*)d_in[1];
  const float* b1  = (const float*)d_in[2];
  const float* w2  = (const float*)d_in[3];
  const float* b2  = (const float*)d_in[4];
  const float* g1  = (const float*)d_in[5];
  const float* be1 = (const float*)d_in[6];
  const float* g2  = (const float*)d_in[7];
  const float* be2 = (const float*)d_in[8];

  float* out_c = (float*)d_out;          // C_out: NPIX floats
  float* out_r = out_c + NPIX;           // R: NM floats

  float* ws = (float*)d_ws;
  size_t off = 0;
  float* p     = ws + off; off += (size_t)B*C*NSP;
  float* E     = ws + off; off += NM;
  float* Sarr  = ws + off; off += NPIX;
  float* y2    = ws + off; off += NPIX;
  float* T     = ws + off; off += NPIX;
  float* G     = ws + off; off += 64*64;  // Gram (padded)
  float* gs    = ws + off; off += 64;     // per-channel sums
  float* stats2= ws + off; off += 2;      // BN2 sum/sumsq
  float* ac    = ws + off; off += 112;    // BN1 scale/shift
  float* a2c2  = ws + off; off += 2;      // BN2 scale/shift

  hipMemsetAsync(G, 0, (64*64 + 64 + 2)*sizeof(float), stream);

  meanexp_kernel<<<(NM+255)/256, 256, 0, stream>>>(x, E);

  dim3 pg(10, 10, B*C);
  pool_kernel<<<pg, 256, 0, stream>>>(x, p, 1.0f/64.0f);

  dim3 sg(10, 10, B);
  pool_kernel<<<sg, 256, 0, stream>>>(E, Sarr, 1.0f);

  gram_kernel<<<512, 256, 0, stream>>>(p, G, gs);
  bn1_from_gram_kernel<<<1, 256, 0, stream>>>(G, gs, w1, b1, g1, be1, ac);
  y2_stats_kernel<<<NCHUNK, 256, 0, stream>>>(p, w1, b1, ac, w2, b2, y2, stats2);
  bn2_final_kernel<<<1, 64, 0, stream>>>(stats2, g2, be2, a2c2);
  cout_t_kernel<<<(NPIX+255)/256, 256, 0, stream>>>(y2, a2c2, Sarr, out_c, T);
  r_kernel<<<(NM+255)/256, 256, 0, stream>>>(E, T, out_r);
}

// Round 3
// 226.866 us; speedup vs baseline: 1.2251x; 1.1050x over previous
//
#include <hip/hip_runtime.h>
#include <math.h>

#define B 4
#define C 56
#define H 320
#define W 320
#define HC 313
#define WC 313
#define NIMG (H*W)          // 102400
#define NSP  (HC*WC)        // 97969
#define NPIX (B*NSP)        // 391876
#define NM   (B*NIMG)       // 409600
#define BN_EPS 1e-5f
#define HALO 39
#define NHALO (HALO*HALO)   // 1521

typedef __attribute__((ext_vector_type(8))) short short8;
typedef __attribute__((ext_vector_type(16))) float float16;

__device__ __forceinline__ unsigned short f2bf(float v) {
  unsigned int u = __float_as_uint(v);
  return (unsigned short)((u + 0x7fffu + ((u >> 16) & 1u)) >> 16);
}
// byte offset of P[c][pix] in the swizzled [64][1024] bf16 tile
__device__ __forceinline__ int pswz(int c, int pix) {
  return c*2048 + ((2*pix) ^ ((c & 15) << 4));
}

// ---------------------------------------------------------------------------
// Pass 1: per 32x32 output tile, one sweep over x:
//   E = exp(mean_c x)  (written for the 32x32 interior)
//   pooled p (8x8 avg, VALID) -> bf16 LDS tile P[64][1024]
//   p_t global [pix][64ch] bf16 (transposed, coalesced)
//   G += P P^T via MFMA; gs[c] += sum(p[c])
// ---------------------------------------------------------------------------
__global__ __launch_bounds__(512) void pass1_kernel(
    const float* __restrict__ x, float* __restrict__ E,
    unsigned short* __restrict__ p_t, float* __restrict__ G,
    float* __restrict__ gs) {
  __shared__ unsigned short P[64*1024];                         // 128 KB
  __shared__ struct { float tin[2][HALO][40]; float hs[HALO][33]; } sb;  // 17628 B
  float* gred = (float*)&sb;                                    // 16 KB overlay (post-loop)
  __shared__ float gsacc[64];

  const int tid = threadIdx.x;
  const int wave = tid >> 6, lane = tid & 63;
  int bid = blockIdx.x;
  const int b = bid / 100; bid -= b*100;
  const int by = bid / 10, bx = bid - by*10;
  const int i0 = by*32, j0 = bx*32;

  if (tid < 64) gsacc[tid] = 0.f;

  const float* xb = x + (size_t)b*C*NIMG;

  int r_[3], c_[3];
  #pragma unroll
  for (int k = 0; k < 3; ++k) {
    int idx = tid + k*512;
    r_[k] = idx / HALO; c_[k] = idx - r_[k]*HALO;
  }
  auto loadch = [&](int c, float& v0, float& v1, float& v2) {
    const float* xp = xb + (size_t)c*NIMG;
    int gi, gj;
    gi = i0 + r_[0]; gj = j0 + c_[0];
    v0 = (gi < H && gj < W) ? xp[gi*W + gj] : 0.f;
    gi = i0 + r_[1]; gj = j0 + c_[1];
    v1 = (gi < H && gj < W) ? xp[gi*W + gj] : 0.f;
    gi = i0 + r_[2]; gj = j0 + c_[2];
    v2 = (tid < NHALO - 1024 && gi < H && gj < W) ? xp[gi*W + gj] : 0.f;
  };

  float cur0, cur1, cur2, csum0 = 0.f, csum1 = 0.f, csum2 = 0.f;
  loadch(0, cur0, cur1, cur2);
  __syncthreads();   // gsacc ready

  for (int c = 0; c < C; ++c) {
    const int buf = c & 1;
    float n0, n1, n2;
    if (c + 1 < C) loadch(c + 1, n0, n1, n2);   // prefetch next channel
    csum0 += cur0; csum1 += cur1; csum2 += cur2;
    sb.tin[buf][r_[0]][c_[0]] = cur0;
    sb.tin[buf][r_[1]][c_[1]] = cur1;
    if (tid < NHALO - 1024) sb.tin[buf][r_[2]][c_[2]] = cur2;
    __syncthreads();
    // horizontal 8-sums: 39x32
    #pragma unroll
    for (int it = 0; it < 3; ++it) {
      int idx = tid + it*512;
      if (idx < HALO*32) {
        int r = idx >> 5, j = idx & 31;
        float s = 0.f;
        #pragma unroll
        for (int d = 0; d < 8; ++d) s += sb.tin[buf][r][j + d];
        sb.hs[r][j] = s;
      }
    }
    __syncthreads();
    // vertical 8-sums -> pooled 32x32, stage bf16 into P
    float vs = 0.f;
    #pragma unroll
    for (int it = 0; it < 2; ++it) {
      int idx = tid + it*512;
      int i = idx >> 5, j = idx & 31;
      float s = 0.f;
      #pragma unroll
      for (int d = 0; d < 8; ++d) s += sb.hs[i + d][j];
      int gi = i0 + i, gj = j0 + j;
      float v = (gi < HC && gj < WC) ? s * (1.f/64.f) : 0.f;
      vs += v;
      *(unsigned short*)((char*)P + pswz(c, idx)) = f2bf(v);
    }
    #pragma unroll
    for (int off = 32; off > 0; off >>= 1) vs += __shfl_down(vs, off);
    if (lane == 0) atomicAdd(&gsacc[c], vs);
    cur0 = n0; cur1 = n1; cur2 = n2;
  }
  __syncthreads();   // P complete; tin/hs dead from here

  // E write (interior 32x32; each global pixel written by exactly one block)
  {
    float cs[3] = {csum0, csum1, csum2};
    #pragma unroll
    for (int k = 0; k < 3; ++k) {
      int r = r_[k], cc = c_[k];
      if (r < 32 && cc < 32)
        E[(size_t)b*NIMG + (i0 + r)*W + (j0 + cc)] = expf(cs[k] * (1.f/C));
    }
  }
  if (tid < C) atomicAdd(&gs[tid], gsacc[tid]);

  // p_t transpose write: [pix][64ch] bf16, 16B per lane, coalesced
  #pragma unroll
  for (int it = 0; it < 16; ++it) {
    int idx = tid + it*512;
    int p = idx >> 3, g = idx & 7;
    int gi = i0 + (p >> 5), gj = j0 + (p & 31);
    if (gi < HC && gj < WC) {
      unsigned short tmp[8];
      #pragma unroll
      for (int kk = 0; kk < 8; ++kk)
        tmp[kk] = *(const unsigned short*)((const char*)P + pswz(g*8 + kk, p));
      *(short8*)(p_t + ((size_t)b*NSP + gi*WC + gj)*64 + g*8) = *(short8*)tmp;
    }
  }

  // Gram: 4 quadrants x 2 K-halves over 8 waves
  const int quad = wave >> 1;
  const int qi = (quad >> 1)*32, qj = (quad & 1)*32;
  const int kh = wave & 1;
  const int rA = qi + (lane & 31), rB = qj + (lane & 31);
  float16 acc = {};
  #pragma unroll
  for (int ks = 0; ks < 32; ++ks) {
    int ka = kh*512 + ks*16 + 8*(lane >> 5);
    short8 a  = *(const short8*)((const char*)P + pswz(rA, ka));
    short8 bb = *(const short8*)((const char*)P + pswz(rB, ka));
    acc = __builtin_amdgcn_mfma_f32_32x32x16_bf16(a, bb, acc, 0, 0, 0);
  }
  if (kh == 1) {
    #pragma unroll
    for (int reg = 0; reg < 16; ++reg) gred[quad*1024 + reg*64 + lane] = acc[reg];
  }
  __syncthreads();
  if (kh == 0) {
    #pragma unroll
    for (int reg = 0; reg < 16; ++reg) {
      float v = acc[reg] + gred[quad*1024 + reg*64 + lane];
      int gr = qi + (reg & 3) + 8*(reg >> 2) + 4*(lane >> 5);
      int gc = qj + (lane & 31);
      atomicAdd(&G[gr*64 + gc], v);
    }
  }
}

// 8x8 sliding box-sum (VALID) for S = boxsum(E)
__global__ __launch_bounds__(256) void pool_kernel(const float* __restrict__ in,
                                                   float* __restrict__ out, float scale) {
  __shared__ float tin[39][40];
  __shared__ float hs[39][33];
  const int z = blockIdx.z;
  const float* ip = in + (size_t)z*NIMG;
  float* op = out + (size_t)z*NSP;
  const int i0 = blockIdx.y*32, j0 = blockIdx.x*32;
  const int tid = threadIdx.x;
  for (int idx = tid; idx < 39*39; idx += 256) {
    int r = idx / 39, cc = idx - r*39;
    int gi = i0 + r, gj = j0 + cc;
    tin[r][cc] = (gi < H && gj < W) ? ip[gi*W + gj] : 0.f;
  }
  __syncthreads();
  for (int idx = tid; idx < 39*32; idx += 256) {
    int r = idx >> 5, j = idx & 31;
    float s = 0.f;
    #pragma unroll
    for (int d = 0; d < 8; ++d) s += tin[r][j+d];
    hs[r][j] = s;
  }
  __syncthreads();
  for (int idx = tid; idx < 32*32; idx += 256) {
    int i = idx >> 5, j = idx & 31;
    int gi = i0 + i, gj = j0 + j;
    if (gi < HC && gj < WC) {
      float s = 0.f;
      #pragma unroll
      for (int d = 0; d < 8; ++d) s += hs[i+d][j];
      op[gi*WC + gj] = s * scale;
    }
  }
}

// BN1 scale/shift analytically from Gram
__global__ __launch_bounds__(256) void bn1_from_gram_kernel(
    const float* __restrict__ G, const float* __restrict__ gs,
    const float* __restrict__ w1, const float* __restrict__ b1,
    const float* __restrict__ g1, const float* __restrict__ be1,
    float* __restrict__ ac) {
  __shared__ float Gl[64*64];
  __shared__ float Wl[C*C];
  __shared__ float Ul[C*C];
  __shared__ float ml[C];
  int tid = threadIdx.x;
  for (int i = tid; i < 64*64; i += 256) Gl[i] = G[i];
  for (int i = tid; i < C*C; i += 256) Wl[i] = w1[i];
  if (tid < C) ml[tid] = gs[tid] * (1.0f/NPIX);
  __syncthreads();
  for (int e = tid; e < C*C; e += 256) {
    int o = e / C, c = e - o*C;
    float s = 0.f;
    for (int c2 = 0; c2 < C; ++c2) s = fmaf(Wl[o*C + c2], Gl[c2*64 + c], s);
    Ul[e] = s;
  }
  __syncthreads();
  if (tid < C) {
    int o = tid;
    float q = 0.f, uw = 0.f;
    for (int c = 0; c < C; ++c) {
      q  = fmaf(Wl[o*C + c], ml[c], q);
      uw = fmaf(Ul[o*C + c], Wl[o*C + c], uw);
    }
    float var = uw * (1.0f/NPIX) - q*q;
    float mean = q + b1[o];
    float a = g1[o] * rsqrtf(var + BN_EPS);
    ac[o]     = a;
    ac[C + o] = fmaf(-mean, a, be1[o]);
  }
}

// y2 via MFMA from p_t; BN1+ReLU+w2-dot epilogue; BN2 stats into 64 bins
#define Y2BLK 128
__global__ __launch_bounds__(256) void y2_mfma_kernel(
    const unsigned short* __restrict__ p_t, const float* __restrict__ w1,
    const float* __restrict__ b1, const float* __restrict__ ac,
    const float* __restrict__ w2, const float* __restrict__ b2,
    float* __restrict__ y2, float* __restrict__ stats2) {
  __shared__ unsigned short Wl[64*64];   // swizzled bf16 w1pad
  __shared__ float af[64], cf[64], wf[64];
  __shared__ float racc[2];
  const int tid = threadIdx.x, wave = tid >> 6, lane = tid & 63;
  for (int idx = tid; idx < 4096; idx += 256) {
    int o = idx >> 6, k = idx & 63;
    float v = (o < C && k < C) ? w1[o*C + k] : 0.f;
    *(unsigned short*)((char*)Wl + (o*128 + ((2*k) ^ ((o & 7) << 4)))) = f2bf(v);
  }
  if (tid < 64) {
    float a = (tid < C) ? ac[tid] : 0.f;
    af[tid] = a;
    cf[tid] = (tid < C) ? fmaf(a, b1[tid], ac[C + tid]) : 0.f;
    wf[tid] = (tid < C) ? w2[tid] : 0.f;
  }
  if (tid < 2) racc[tid] = 0.f;
  __syncthreads();
  short8 afr[2][4];
  #pragma unroll
  for (int q = 0; q < 2; ++q) {
    #pragma unroll
    for (int ks = 0; ks < 4; ++ks) {
      int row = q*32 + (lane & 31), kb = ks*16 + 8*(lane >> 5);
      afr[q][ks] = *(const short8*)((const char*)Wl + row*128 + ((2*kb) ^ ((row & 7) << 4)));
    }
  }
  int col = blockIdx.x*Y2BLK + wave*32 + (lane & 31);
  bool cvalid = col < NPIX;
  int ccol = cvalid ? col : NPIX - 1;
  const unsigned short* pr = p_t + (size_t)ccol*64;
  short8 bfr[4];
  #pragma unroll
  for (int ks = 0; ks < 4; ++ks)
    bfr[ks] = *(const short8*)(pr + ks*16 + 8*(lane >> 5));
  if (lane >= 32) bfr[3] = (short8){0,0,0,0,0,0,0,0};   // ch 56..63 pad
  float16 acc0 = {}, acc1 = {};
  #pragma unroll
  for (int ks = 0; ks < 4; ++ks) {
    acc0 = __builtin_amdgcn_mfma_f32_32x32x16_bf16(afr[0][ks], bfr[ks], acc0, 0, 0, 0);
    acc1 = __builtin_amdgcn_mfma_f32_32x32x16_bf16(afr[1][ks], bfr[ks], acc1, 0, 0, 0);
  }
  float ysum = 0.f;
  #pragma unroll
  for (int reg = 0; reg < 16; ++reg) {
    int o0 = (reg & 3) + 8*(reg >> 2) + 4*(lane >> 5);
    float t0 = fmaf(af[o0], acc0[reg], cf[o0]);
    ysum = fmaf(wf[o0], fmaxf(t0, 0.f), ysum);
    int o1 = o0 + 32;
    float t1 = fmaf(af[o1], acc1[reg], cf[o1]);
    ysum = fmaf(wf[o1], fmaxf(t1, 0.f), ysum);
  }
  ysum += __shfl_xor(ysum, 32);
  ysum += b2[0];
  bool wr = cvalid && lane < 32;
  if (wr) y2[col] = ysum;
  float s1 = wr ? ysum : 0.f;
  float s2 = wr ? ysum*ysum : 0.f;
  #pragma unroll
  for (int off = 32; off > 0; off >>= 1) {
    s1 += __shfl_down(s1, off);
    s2 += __shfl_down(s2, off);
  }
  if (lane == 0) { atomicAdd(&racc[0], s1); atomicAdd(&racc[1], s2); }
  __syncthreads();
  if (tid < 2) atomicAdd(&stats2[(blockIdx.x & 63)*2 + tid], racc[tid]);
}

__global__ void bn2_final_kernel(const float* __restrict__ stats2,
                                 const float* __restrict__ g2, const float* __restrict__ be2,
                                 float* __restrict__ a2c2) {
  int t = threadIdx.x;   // 64 threads
  float s1 = stats2[t*2], s2 = stats2[t*2 + 1];
  #pragma unroll
  for (int off = 32; off > 0; off >>= 1) {
    s1 += __shfl_down(s1, off);
    s2 += __shfl_down(s2, off);
  }
  if (t == 0) {
    float mean = s1 * (1.0f/NPIX);
    float var  = s2 * (1.0f/NPIX) - mean*mean;
    float a = g2[0] * rsqrtf(var + BN_EPS);
    a2c2[0] = a;
    a2c2[1] = fmaf(-mean, a, be2[0]);
  }
}

// C_out = relu(a2*y2 + c2) -> d_out; T = C_out / S
__global__ __launch_bounds__(256) void cout_t_kernel(
    const float* __restrict__ y2, const float* __restrict__ a2c2,
    const float* __restrict__ S, float* __restrict__ cout, float* __restrict__ T) {
  int idx = blockIdx.x*256 + threadIdx.x;
  if (idx >= NPIX) return;
  float v = fmaxf(fmaf(a2c2[0], y2[idx], a2c2[1]), 0.f);
  cout[idx] = v;
  T[idx] = v / S[idx];
}

// R = E * fullcorr8x8(T)  (separable box-sum of zero-padded T, offset -7)
__global__ __launch_bounds__(256) void r_pool_kernel(const float* __restrict__ T,
                                                     const float* __restrict__ E,
                                                     float* __restrict__ R) {
  __shared__ float tin[39][40];
  __shared__ float hs[39][33];
  const int z = blockIdx.z;
  const float* Tb = T + (size_t)z*NSP;
  const int i0 = blockIdx.y*32, j0 = blockIdx.x*32;
  const int tid = threadIdx.x;
  for (int idx = tid; idx < 39*39; idx += 256) {
    int r = idx / 39, cc = idx - r*39;
    int gi = i0 + r - 7, gj = j0 + cc - 7;
    tin[r][cc] = (gi >= 0 && gi < HC && gj >= 0 && gj < WC) ? Tb[gi*WC + gj] : 0.f;
  }
  __syncthreads();
  for (int idx = tid; idx < 39*32; idx += 256) {
    int r = idx >> 5, j = idx & 31;
    float s = 0.f;
    #pragma unroll
    for (int d = 0; d < 8; ++d) s += tin[r][j+d];
    hs[r][j] = s;
  }
  __syncthreads();
  for (int idx = tid; idx < 32*32; idx += 256) {
    int i = idx >> 5, j = idx & 31;
    size_t gofs = (size_t)z*NIMG + (i0 + i)*W + (j0 + j);
    float s = 0.f;
    #pragma unroll
    for (int d = 0; d < 8; ++d) s += hs[i+d][j];
    R[gofs] = E[gofs] * s;
  }
}

extern "C" void kernel_launch(void* const* d_in, const int* in_sizes, int n_in,
                              void* d_out, int out_size, void* d_ws, size_t ws_size,
                              hipStream_t stream) {
  const float* x   = (const float*)d_in[0];
  const float* w1  = (const float*)d_in[1];
  const float* b1  = (const float*)d_in[2];
  const float* w2  = (const float*)d_in[3];
  const float* b2  = (const float*)d_in[4];
  const float* g1  = (const float*)d_in[5];
  const float* be1 = (const float*)d_in[6];
  const float* g2  = (const float*)d_in[7];
  const float* be2 = (const float*)d_in[8];

  float* out_c = (float*)d_out;          // C_out: NPIX floats
  float* out_r = out_c + NPIX;           // R: NM floats

  unsigned short* p_t = (unsigned short*)d_ws;          // [NPIX][64] bf16
  float* fbase = (float*)(p_t + (size_t)NPIX*64);
  size_t off = 0;
  float* E      = fbase + off; off += NM;
  float* Sarr   = fbase + off; off += NPIX;
  float* y2     = fbase + off; off += NPIX;
  float* T      = fbase + off; off += NPIX;
  float* G      = fbase + off; off += 64*64;
  float* gs     = fbase + off; off += 64;
  float* stats2 = fbase + off; off += 128;
  float* ac     = fbase + off; off += 112;
  float* a2c2   = fbase + off; off += 2;

  hipMemsetAsync(G, 0, (64*64 + 64 + 128)*sizeof(float), stream);

  pass1_kernel<<<400, 512, 0, stream>>>(x, E, p_t, G, gs);

  dim3 sg(10, 10, B);
  pool_kernel<<<sg, 256, 0, stream>>>(E, Sarr, 1.0f);

  bn1_from_gram_kernel<<<1, 256, 0, stream>>>(G, gs, w1, b1, g1, be1, ac);

  y2_mfma_kernel<<<(NPIX + Y2BLK - 1)/Y2BLK, 256, 0, stream>>>(
      p_t, w1, b1, ac, w2, b2, y2, stats2);

  bn2_final_kernel<<<1, 64, 0, stream>>>(stats2, g2, be2, a2c2);
  cout_t_kernel<<<(NPIX + 255)/256, 256, 0, stream>>>(y2, a2c2, Sarr, out_c, T);

  dim3 rg(10, 10, B);
  r_pool_kernel<<<rg, 256, 0, stream>>>(T, E, out_r);
}